// Round 10
// baseline (511.070 us; speedup 1.0000x reference)
//
#include <hip/hip_runtime.h>
#include <cstdint>
#include <cstddef>

typedef __attribute__((ext_vector_type(8))) short short8;
typedef __attribute__((ext_vector_type(4))) float f32x4;
typedef __attribute__((ext_vector_type(4))) _Float16 half4v;
typedef __attribute__((ext_vector_type(2))) _Float16 half2v;

// ---------------- bf16 split helpers (round-to-nearest-even) ----------------

__device__ inline unsigned short f2bf(float f) {
    unsigned int u = __float_as_uint(f);
    u = u + 0x7fff + ((u >> 16) & 1);
    return (unsigned short)(u >> 16);
}
__device__ inline float bf2f(unsigned short h) {
    return __uint_as_float(((unsigned int)h) << 16);
}
__device__ inline void split2(float v, unsigned short& hi, unsigned short& lo) {
    hi = f2bf(v);
    lo = f2bf(v - bf2f(hi));
}

// ---------------- preprocessing kernels ----------------

__global__ void zero_ints(int* p, int n) {
    int i = blockIdx.x * 256 + threadIdx.x;
    if (i < n) p[i] = 0;
}

__global__ void count_deg(const int* __restrict__ dst, int* __restrict__ cnt, int E) {
    int i = blockIdx.x * 256 + threadIdx.x;
    if (i < E) atomicAdd(&cnt[dst[i]], 1);
}

__global__ void compute_dis(const int* __restrict__ cnt, float* __restrict__ dis, int N) {
    int i = blockIdx.x * 256 + threadIdx.x;
    if (i < N) dis[i] = rsqrtf((float)cnt[i] + 1.0f);
}

// ---------------- 3-phase parallel exclusive scan over cnt -> rp, cursor ----------------

__global__ __launch_bounds__(256) void scan_block_sums(const int* __restrict__ cnt,
                                                       int* __restrict__ partials, int N) {
    __shared__ int s[256];
    int t = threadIdx.x;
    int base = blockIdx.x * 1024 + t * 4;
    int v = 0;
    if (base + 3 < N) {
        int4 d = *(const int4*)&cnt[base];
        v = d.x + d.y + d.z + d.w;
    } else {
        for (int j = 0; j < 4; ++j) if (base + j < N) v += cnt[base + j];
    }
    s[t] = v;
    __syncthreads();
    for (int off = 128; off > 0; off >>= 1) {
        if (t < off) s[t] += s[t + off];
        __syncthreads();
    }
    if (t == 0) partials[blockIdx.x] = s[0];
}

__global__ __launch_bounds__(256) void scan_partials(int* __restrict__ partials, int nb,
                                                     int* __restrict__ rp, int N) {
    __shared__ int s[256];
    int t = threadIdx.x;
    int base = t * 4;
    int v0 = 0, v1 = 0, v2 = 0, v3 = 0;
    if (base < nb)     v0 = partials[base];
    if (base + 1 < nb) v1 = partials[base + 1];
    if (base + 2 < nb) v2 = partials[base + 2];
    if (base + 3 < nb) v3 = partials[base + 3];
    s[t] = v0 + v1 + v2 + v3;
    __syncthreads();
    for (int off = 1; off < 256; off <<= 1) {
        int v = s[t];
        int u = (t >= off) ? s[t - off] : 0;
        __syncthreads();
        s[t] = v + u;
        __syncthreads();
    }
    int run = (t == 0) ? 0 : s[t - 1];
    if (base < nb)     { partials[base] = run;     run += v0; }
    if (base + 1 < nb) { partials[base + 1] = run; run += v1; }
    if (base + 2 < nb) { partials[base + 2] = run; run += v2; }
    if (base + 3 < nb) { partials[base + 3] = run; run += v3; }
    if (t == 255) rp[N] = s[255];
}

__global__ __launch_bounds__(256) void scan_write(const int* __restrict__ cnt,
                                                  const int* __restrict__ partials,
                                                  int* __restrict__ rp,
                                                  int* __restrict__ cursor, int N) {
    __shared__ int s[256];
    int t = threadIdx.x;
    int base = blockIdx.x * 1024 + t * 4;
    int v0 = 0, v1 = 0, v2 = 0, v3 = 0;
    if (base + 3 < N) {
        int4 d = *(const int4*)&cnt[base];
        v0 = d.x; v1 = d.y; v2 = d.z; v3 = d.w;
    } else {
        if (base < N)     v0 = cnt[base];
        if (base + 1 < N) v1 = cnt[base + 1];
        if (base + 2 < N) v2 = cnt[base + 2];
    }
    s[t] = v0 + v1 + v2 + v3;
    __syncthreads();
    for (int off = 1; off < 256; off <<= 1) {
        int v = s[t];
        int u = (t >= off) ? s[t - off] : 0;
        __syncthreads();
        s[t] = v + u;
        __syncthreads();
    }
    int run = partials[blockIdx.x] + ((t == 0) ? 0 : s[t - 1]);
    int4 o;
    o.x = run; run += v0;
    o.y = run; run += v1;
    o.z = run; run += v2;
    o.w = run; run += v3;
    if (base + 3 < N) {
        *(int4*)&rp[base] = o;
        *(int4*)&cursor[base] = o;
    } else {
        if (base < N)     { rp[base] = o.x;     cursor[base] = o.x; }
        if (base + 1 < N) { rp[base + 1] = o.y; cursor[base + 1] = o.y; }
        if (base + 2 < N) { rp[base + 2] = o.z; cursor[base + 2] = o.z; }
    }
}

// edata[pos] = (src, bitcast(norm)) — one 8B record per edge
__global__ void scatter_edges(const int* __restrict__ src, const int* __restrict__ dstv,
                              const float* __restrict__ dis, int* __restrict__ cursor,
                              int2* __restrict__ edata, int E) {
    int i = blockIdx.x * 256 + threadIdx.x;
    if (i < E) {
        int s = src[i], d = dstv[i];
        int pos = atomicAdd(&cursor[d], 1);
        edata[pos] = make_int2(s, __float_as_int(dis[s] * dis[d]));
    }
}

__global__ void build_h0(const float* __restrict__ x, const float* __restrict__ xm,
                         float* __restrict__ h0, int N) {
    int i = blockIdx.x * 256 + threadIdx.x;
    if (i < N * 16) {
        int node = i >> 4, f = i & 15;
        h0[i] = (f < 8) ? x[node * 10 + f] : xm[node * 10 + f - 8];
    }
}

// ---------------- W split into MFMA B-fragment order ----------------

__global__ __launch_bounds__(256) void wsplit_kernel(const float* __restrict__ Wh,
                                                     const float* __restrict__ Wr1,
                                                     unsigned short* __restrict__ whi,
                                                     unsigned short* __restrict__ wlo) {
    int g = blockIdx.x * 256 + threadIdx.x;   // 5*16384 entries
    int l = g >> 14;
    int idx = g & 16383;
    int j = idx & 7;
    int lane = (idx >> 3) & 63;
    int tcchunk = idx >> 9;                   // 0..31
    int tc = tcchunk & 7, chunk = tcchunk >> 3;
    int k = chunk * 32 + (lane >> 4) * 8 + j;
    int n = tc * 16 + (lane & 15);
    float v = (l < 4) ? Wh[l * 16384 + k * 128 + n] : Wr1[k * 128 + n];
    unsigned short hi, lo;
    split2(v, hi, lo);
    whi[g] = hi;
    wlo[g] = lo;
}

// ---------------- per-node aggregation bodies (forceinline; callers fully unroll
// so every array access is compile-time-constant — rule #20) ----------------

__device__ __forceinline__ float agg_node_l0(
    const float* __restrict__ h0, const int2* __restrict__ edata,
    const float* __restrict__ dis,
    int node, int beg, int deg, int es, int f, int N) {
    float acc = 0.f;
    if (node < N) {
        float di = dis[node];
        float sf = h0[(size_t)node * 16 + f];
        acc = (es == 0) ? sf * (di * di) : 0.f;
        const int2* ep = edata + beg;
        for (int eb = 0; eb < deg; eb += 16) {
            int2 rec[16];
            #pragma unroll
            for (int j = 0; j < 16; ++j) rec[j] = ep[eb + j];
            int c = min(deg - eb, 16);   // >= 1
            int ixs = rec[0].x;
            float vv[4], nn[4];
            #pragma unroll
            for (int b = 0; b < 4; ++b) {
                // constant-index reads of rec; per-lane es select via cndmask
                int x0 = rec[b * 4 + 0].x, x1 = rec[b * 4 + 1].x;
                int x2 = rec[b * 4 + 2].x, x3 = rec[b * 4 + 3].x;
                int y0 = rec[b * 4 + 0].y, y1 = rec[b * 4 + 1].y;
                int y2 = rec[b * 4 + 2].y, y3 = rec[b * 4 + 3].y;
                int ix = (es == 0) ? x0 : (es == 1) ? x1 : (es == 2) ? x2 : x3;
                int iy = (es == 0) ? y0 : (es == 1) ? y1 : (es == 2) ? y2 : y3;
                int j = b * 4 + es;
                ix = (j < c) ? ix : ixs;
                vv[b] = h0[(size_t)ix * 16 + f];
                nn[b] = (j < c) ? __int_as_float(iy) : 0.f;
            }
            #pragma unroll
            for (int b = 0; b < 4; ++b) acc += nn[b] * vv[b];
        }
    }
    acc += __shfl_xor(acc, 16);
    acc += __shfl_xor(acc, 32);
    return acc;
}

__device__ __forceinline__ void store_row_hidden(unsigned short* sAh, unsigned short* sAl,
                                                 int r, int ln, float a0, float a1) {
    unsigned short h0_, l0_, h1_, l1_;
    split2(a0, h0_, l0_);
    split2(a1, h1_, l1_);
    int bo = (r * 256 + ln * 4) ^ ((r & 7) << 4);
    ushort2 hh; hh.x = h0_; hh.y = h1_;
    ushort2 ll; ll.x = l0_; ll.y = l1_;
    *(ushort2*)((char*)sAh + bo) = hh;
    *(ushort2*)((char*)sAl + bo) = ll;
}

// Pair of nodes per call: BOTH scalar edge bursts issue before the single
// lgkmcnt(0) drain (SMEM is out-of-order -> any use drains ALL s_loads; one
// drain per pair instead of per node). Gathers staggered A[0:8),B[0:8),A[8:16)
// before the first FMA -> up to 32 loads in flight, <=24 va VGPRs live.
// FP order per node: self, edges ascending, tail — bit-identical to R5/R8/R9.
// j>=c gathers use the (valid) self node index with norm 0 -> exact no-op.

__device__ __forceinline__ void agg_pair_hidden(
    const half2v* __restrict__ hb, const int2* __restrict__ edata,
    const float* __restrict__ dis,
    int nodeA, int begA, int degA,
    int nodeB, int begB, int degB,
    int ln, int N,
    unsigned short* sAh, unsigned short* sAl, int rA, int rB) {
    bool vA = nodeA < N, vB = nodeB < N;
    int nA = vA ? nodeA : 0;
    int nB = vB ? nodeB : 0;
    int cA = vA ? min(degA, 16) : 0;
    int cB = vB ? min(degB, 16) : 0;
    const int2* epA = edata + begA;
    const int2* epB = edata + begB;
    // two wave-uniform scalar bursts, back-to-back (single lgkm drain)
    int2 recA[16], recB[16];
    #pragma unroll
    for (int j = 0; j < 16; ++j) recA[j] = epA[j];
    #pragma unroll
    for (int j = 0; j < 16; ++j) recB[j] = epB[j];
    half2v svA = hb[(size_t)nA * 64 + ln];
    half2v svB = hb[(size_t)nB * 64 + ln];
    float dA = dis[nA], dB = dis[nB];
    // stagger gathers: A0, B0, A1 issued before first FMA
    half2v vaA0[8], vaB0[8], vaA1[8], vaB1[8];
    #pragma unroll
    for (int j = 0; j < 8; ++j) {
        int ix = (j < cA) ? recA[j].x : nA;
        vaA0[j] = hb[(size_t)ix * 64 + ln];
    }
    #pragma unroll
    for (int j = 0; j < 8; ++j) {
        int ix = (j < cB) ? recB[j].x : nB;
        vaB0[j] = hb[(size_t)ix * 64 + ln];
    }
    #pragma unroll
    for (int j = 0; j < 8; ++j) {
        int ix = (j + 8 < cA) ? recA[j + 8].x : nA;
        vaA1[j] = hb[(size_t)ix * 64 + ln];
    }
    float scA = vA ? dA * dA : 0.f;
    float a0A = (float)svA[0] * scA;
    float a1A = (float)svA[1] * scA;
    #pragma unroll
    for (int j = 0; j < 8; ++j) {
        float nr = (j < cA) ? __int_as_float(recA[j].y) : 0.f;
        a0A += nr * (float)vaA0[j][0];
        a1A += nr * (float)vaA0[j][1];
    }
    #pragma unroll
    for (int j = 0; j < 8; ++j) {
        int ix = (j + 8 < cB) ? recB[j + 8].x : nB;
        vaB1[j] = hb[(size_t)ix * 64 + ln];
    }
    float scB = vB ? dB * dB : 0.f;
    float a0B = (float)svB[0] * scB;
    float a1B = (float)svB[1] * scB;
    #pragma unroll
    for (int j = 0; j < 8; ++j) {
        float nr = (j < cB) ? __int_as_float(recB[j].y) : 0.f;
        a0B += nr * (float)vaB0[j][0];
        a1B += nr * (float)vaB0[j][1];
    }
    #pragma unroll
    for (int j = 0; j < 8; ++j) {
        float nr = (j + 8 < cA) ? __int_as_float(recA[j + 8].y) : 0.f;
        a0A += nr * (float)vaA1[j][0];
        a1A += nr * (float)vaA1[j][1];
    }
    #pragma unroll
    for (int j = 0; j < 8; ++j) {
        float nr = (j + 8 < cB) ? __int_as_float(recB[j + 8].y) : 0.f;
        a0B += nr * (float)vaB1[j][0];
        a1B += nr * (float)vaB1[j][1];
    }
    // rare deg>16 tails, ascending order
    if (vA && degA > 16) {
        for (int e = 16; e < degA; ++e) {
            int2 r2 = epA[e];
            half2v v = hb[(size_t)r2.x * 64 + ln];
            float nr = __int_as_float(r2.y);
            a0A += nr * (float)v[0];
            a1A += nr * (float)v[1];
        }
    }
    if (vB && degB > 16) {
        for (int e = 16; e < degB; ++e) {
            int2 r2 = epB[e];
            half2v v = hb[(size_t)r2.x * 64 + ln];
            float nr = __int_as_float(r2.y);
            a0B += nr * (float)v[0];
            a1B += nr * (float)v[1];
        }
    }
    store_row_hidden(sAh, sAl, rA, ln, a0A, a1A);
    store_row_hidden(sAh, sAl, rB, ln, a0B, a1B);
}

// ---------------- fused layer 0: agg16 (wave-scalar) + K=16 VALU GEMM + relu ----------------
// 32 nodes/block, 4 waves. Phase 1: one wave per node, 64 lanes = 4 edge-slots(es)
// x 16 features(f). rp[9] hoisted in ONE round trip; 8-node loop FULLY UNROLLED so
// rr[] is constant-indexed (SGPRs, no scratch — R6/R7 lesson).
// Phase 2: 32x128 output, 256 threads x 16 cols each, W0 staged in LDS.

__global__ __launch_bounds__(256, 8) void fused_layer0_kernel(
    const float* __restrict__ h0,
    const int* __restrict__ rp, const int2* __restrict__ edata,
    const float* __restrict__ dis,
    const float* __restrict__ W0, const float* __restrict__ b0,
    _Float16* __restrict__ hout, int N) {
    __shared__ float sA[32][17];
    __shared__ float sW[2048];
    int t = threadIdx.x;
    int node0 = blockIdx.x * 32;
    // stage W0 (16 x 128)
    for (int i = t * 4; i < 2048; i += 1024)
        *(float4*)&sW[i] = *(const float4*)&W0[i];

    // ---- phase 1 ----
    {
        int wv = __builtin_amdgcn_readfirstlane(t >> 6);
        int ln = t & 63;
        int es = ln >> 4, f = ln & 15;
        int base = node0 + wv * 8;
        int rr[9];
        #pragma unroll
        for (int i = 0; i < 9; ++i) rr[i] = rp[min(base + i, N)];
        #pragma unroll
        for (int it = 0; it < 8; ++it) {
            float acc = agg_node_l0(h0, edata, dis, base + it, rr[it],
                                    rr[it + 1] - rr[it], es, f, N);
            if (es == 0) sA[wv * 8 + it][f] = acc;
        }
    }
    __syncthreads();

    // ---- phase 2: K=16 GEMM ----
    int r2 = t >> 3;
    int c0 = (t & 7) * 16;
    float a16[16];
    #pragma unroll
    for (int c = 0; c < 16; ++c) a16[c] = 0.f;
    #pragma unroll
    for (int k = 0; k < 16; ++k) {
        float a = sA[r2][k];
        #pragma unroll
        for (int c = 0; c < 16; ++c) a16[c] += a * sW[k * 128 + c0 + c];
    }
    int row = node0 + r2;
    if (row < N) {
        #pragma unroll
        for (int cc = 0; cc < 16; cc += 4) {
            half4v o;
            #pragma unroll
            for (int u = 0; u < 4; ++u)
                o[u] = (_Float16)fmaxf(a16[cc + u] + b0[c0 + cc + u], 0.f);
            *(half4v*)&hout[(size_t)row * 128 + c0 + cc] = o;
        }
    }
}

// ---------------- fused layer: aggregate(hin) -> LDS split-bf16 -> MFMA GEMM ----------------
// 32 nodes/block, 16 KB LDS, 8 blocks/CU.
// Phase 1 (wave-scalar, PAIRED bursts): one wave per node-pair iteration; see
// agg_pair_hidden. rp[9] hoisted, 4-pair loop fully unrolled (constant indices).
// Phase 2: 4 waves = (row-group rg, col-half ch); each wave does 16 rows x 4 tc.
// LAST: emb fp32 + fused head (Wr1 MFMA + Wr2 reduce; cross-ch partials via LDS).

template <bool LAST>
__global__ __launch_bounds__(256, 8) void fused_layer_kernel(
    const _Float16* __restrict__ hin,
    const int* __restrict__ rp, const int2* __restrict__ edata,
    const float* __restrict__ dis,
    const unsigned short* __restrict__ whi, const unsigned short* __restrict__ wlo,
    const float* __restrict__ bias,
    void* __restrict__ outv,
    const unsigned short* __restrict__ w1hi, const unsigned short* __restrict__ w1lo,
    const float* __restrict__ br1, const float* __restrict__ Wr2,
    const float* __restrict__ br2, float* __restrict__ pred,
    int N) {
    __shared__ unsigned short sAh[4096];   // 32 rows x 128 cols, swizzled
    __shared__ unsigned short sAl[4096];
    int t = threadIdx.x;
    int node0 = blockIdx.x * 32;

    // ---- phase 1: aggregation into LDS (one wave per node, paired bursts) ----
    {
        int wv1 = __builtin_amdgcn_readfirstlane(t >> 6);
        int ln = t & 63;
        const half2v* hb = (const half2v*)hin;
        int base = node0 + wv1 * 8;
        int rr[9];
        #pragma unroll
        for (int i = 0; i < 9; ++i) rr[i] = rp[min(base + i, N)];
        #pragma unroll
        for (int p = 0; p < 4; ++p) {
            agg_pair_hidden(hb, edata, dis,
                            base + 2 * p,     rr[2 * p],     rr[2 * p + 1] - rr[2 * p],
                            base + 2 * p + 1, rr[2 * p + 1], rr[2 * p + 2] - rr[2 * p + 1],
                            ln, N, sAh, sAl, wv1 * 8 + 2 * p, wv1 * 8 + 2 * p + 1);
        }
    }
    __syncthreads();

    // ---- phase 2: MFMA GEMM from LDS ----
    int wv = t >> 6, ln2 = t & 63;
    int m = ln2 & 15, q = ln2 >> 4;
    int rg = wv & 1, ch = wv >> 1;
    int rloc = rg * 16 + m;
    int tcb = ch * 4;

    f32x4 acc[4];
    #pragma unroll
    for (int i = 0; i < 4; ++i) acc[i] = (f32x4)(0.f);

    #pragma unroll
    for (int chunk = 0; chunk < 4; ++chunk) {
        int bo = (rloc * 256 + q * 16 + chunk * 64) ^ ((rloc & 7) << 4);
        short8 af = *(const short8*)((const char*)sAh + bo);
        short8 lf = *(const short8*)((const char*)sAl + bo);
        const unsigned short* wb = whi + (size_t)(chunk * 8 + tcb) * 512 + ln2 * 8;
        const unsigned short* wc = wlo + (size_t)(chunk * 8 + tcb) * 512 + ln2 * 8;
        #pragma unroll
        for (int j = 0; j < 4; ++j) {
            short8 wh = *(const short8*)(wb + j * 512);
            short8 wl = *(const short8*)(wc + j * 512);
            acc[j] = __builtin_amdgcn_mfma_f32_16x16x32_bf16(af, wh, acc[j], 0, 0, 0);
            acc[j] = __builtin_amdgcn_mfma_f32_16x16x32_bf16(lf, wh, acc[j], 0, 0, 0);
            acc[j] = __builtin_amdgcn_mfma_f32_16x16x32_bf16(af, wl, acc[j], 0, 0, 0);
        }
    }

    // C/D layout: col = lane&15, row = (lane>>4)*4 + reg  [m89/m91-verified]
    int crow = node0 + rg * 16 + q * 4;

    if constexpr (!LAST) {
        _Float16* hout = (_Float16*)outv;
        #pragma unroll
        for (int j = 0; j < 4; ++j) {
            int col = (tcb + j) * 16 + m;
            float b = bias[col];
            #pragma unroll
            for (int r = 0; r < 4; ++r) {
                int rr = crow + r;
                if (rr < N) {
                    float v = fmaxf(acc[j][r] + b, 0.f);
                    hout[(size_t)rr * 128 + col] = (_Float16)v;
                }
            }
        }
    } else {
        __shared__ float pbuf[2][16][3];
        // emb write: fp32 nontemporal, no relu
        float* emb = (float*)outv;
        #pragma unroll
        for (int j = 0; j < 4; ++j) {
            int col = (tcb + j) * 16 + m;
            float b = bias[col];
            #pragma unroll
            for (int r = 0; r < 4; ++r) {
                int rr = crow + r;
                if (rr < N)
                    __builtin_nontemporal_store(acc[j][r] + b, &emb[(size_t)rr * 128 + col]);
            }
        }
        __syncthreads();  // all phase-2 LDS reads complete before overwrite
        // relu + split acc back into LDS (C-layout -> A-layout redistribution)
        #pragma unroll
        for (int j = 0; j < 4; ++j) {
            int col = (tcb + j) * 16 + m;
            float b = bias[col];
            #pragma unroll
            for (int r = 0; r < 4; ++r) {
                int r2 = rg * 16 + q * 4 + r;
                float v = fmaxf(acc[j][r] + b, 0.f);
                unsigned short hi, lo;
                split2(v, hi, lo);
                int bo = (r2 * 256 + col * 2) ^ ((r2 & 7) << 4);
                *(unsigned short*)((char*)sAh + bo) = hi;
                *(unsigned short*)((char*)sAl + bo) = lo;
            }
        }
        __syncthreads();
        // head MFMA: relu(emb) @ Wr1 (this wave's 4 tc columns)
        f32x4 acc2[4];
        #pragma unroll
        for (int i = 0; i < 4; ++i) acc2[i] = (f32x4)(0.f);
        #pragma unroll
        for (int chunk = 0; chunk < 4; ++chunk) {
            int bo = (rloc * 256 + q * 16 + chunk * 64) ^ ((rloc & 7) << 4);
            short8 af = *(const short8*)((const char*)sAh + bo);
            short8 lf = *(const short8*)((const char*)sAl + bo);
            const unsigned short* wb = w1hi + (size_t)(chunk * 8 + tcb) * 512 + ln2 * 8;
            const unsigned short* wc = w1lo + (size_t)(chunk * 8 + tcb) * 512 + ln2 * 8;
            #pragma unroll
            for (int j = 0; j < 4; ++j) {
                short8 wh = *(const short8*)(wb + j * 512);
                short8 wl = *(const short8*)(wc + j * 512);
                acc2[j] = __builtin_amdgcn_mfma_f32_16x16x32_bf16(af, wh, acc2[j], 0, 0, 0);
                acc2[j] = __builtin_amdgcn_mfma_f32_16x16x32_bf16(lf, wh, acc2[j], 0, 0, 0);
                acc2[j] = __builtin_amdgcn_mfma_f32_16x16x32_bf16(af, wl, acc2[j], 0, 0, 0);
            }
        }
        // relu(h @ Wr1 + br1) @ Wr2 + br2: partial over this wave's 64 cols
        float p0[4] = {0.f, 0.f, 0.f, 0.f};
        float p1[4] = {0.f, 0.f, 0.f, 0.f};
        float p2[4] = {0.f, 0.f, 0.f, 0.f};
        #pragma unroll
        for (int j = 0; j < 4; ++j) {
            int col = (tcb + j) * 16 + m;
            float b1 = br1[col];
            float w0 = Wr2[col * 3 + 0], w1 = Wr2[col * 3 + 1], w2 = Wr2[col * 3 + 2];
            #pragma unroll
            for (int r = 0; r < 4; ++r) {
                float hv = fmaxf(acc2[j][r] + b1, 0.f);
                p0[r] += hv * w0;
                p1[r] += hv * w1;
                p2[r] += hv * w2;
            }
        }
        #pragma unroll
        for (int mask = 1; mask < 16; mask <<= 1) {
            #pragma unroll
            for (int r = 0; r < 4; ++r) {
                p0[r] += __shfl_xor(p0[r], mask);
                p1[r] += __shfl_xor(p1[r], mask);
                p2[r] += __shfl_xor(p2[r], mask);
            }
        }
        if (ch == 1 && m == 0) {
            #pragma unroll
            for (int r = 0; r < 4; ++r) {
                pbuf[rg][q * 4 + r][0] = p0[r];
                pbuf[rg][q * 4 + r][1] = p1[r];
                pbuf[rg][q * 4 + r][2] = p2[r];
            }
        }
        __syncthreads();
        if (ch == 0 && m == 0) {
            #pragma unroll
            for (int r = 0; r < 4; ++r) {
                int rr = crow + r;
                if (rr < N) {
                    float o0 = p0[r] + pbuf[rg][q * 4 + r][0] + br2[0];
                    float o1 = p1[r] + pbuf[rg][q * 4 + r][1] + br2[1];
                    float o2 = p2[r] + pbuf[rg][q * 4 + r][2] + br2[2];
                    __builtin_nontemporal_store(o0, &pred[(size_t)rr * 3 + 0]);
                    __builtin_nontemporal_store(o1, &pred[(size_t)rr * 3 + 1]);
                    __builtin_nontemporal_store(o2, &pred[(size_t)rr * 3 + 2]);
                }
            }
        }
    }
}

// ---------------- launch ----------------

extern "C" void kernel_launch(void* const* d_in, const int* in_sizes, int n_in,
                              void* d_out, int out_size, void* d_ws, size_t ws_size,
                              hipStream_t stream) {
    const float* x   = (const float*)d_in[0];
    const float* xm  = (const float*)d_in[1];
    const int*   ei  = (const int*)d_in[2];
    const float* W0  = (const float*)d_in[3];
    const float* b0  = (const float*)d_in[4];
    const float* Wh  = (const float*)d_in[5];
    const float* bh  = (const float*)d_in[6];
    const float* Wr1 = (const float*)d_in[7];
    const float* br1 = (const float*)d_in[8];
    const float* Wr2 = (const float*)d_in[9];
    const float* br2 = (const float*)d_in[10];
    float* out = (float*)d_out;

    int N = in_sizes[0] / 10;
    int E = in_sizes[2] / 2;
    const int* src = ei;
    const int* dst = ei + E;

    float* emb_out  = out;                   // N x 128 (final GCN layer writes here)
    float* pred_out = out + (size_t)N * 128; // N x 3

    char* ws = (char*)d_ws;
    size_t off = 0;
    auto alloc = [&](size_t bytes) -> void* {
        void* p = ws + off;
        off += (bytes + 255) & ~(size_t)255;
        return p;
    };
    // h ping-pong buffers (fp16, 25.6 MB each). h0 aliases bufB's head
    // (dead before bufB's first write at layer l=0's output).
    _Float16* bufA = (_Float16*)alloc((size_t)N * 128 * 2);
    _Float16* bufB = (_Float16*)alloc((size_t)N * 128 * 2);
    float* h0       = (float*)bufB;
    int*   cnt      = (int*)alloc((size_t)N * 4);
    float* dis      = (float*)alloc((size_t)N * 4);
    int*   rp       = (int*)alloc((size_t)(N + 1) * 4);
    int*   cursor   = (int*)alloc((size_t)N * 4);
    int2*  edata    = (int2*)alloc((size_t)E * 8);
    int*   partials = (int*)alloc((size_t)1024 * 4);
    unsigned short* whi = (unsigned short*)alloc((size_t)5 * 16384 * 2);
    unsigned short* wlo = (unsigned short*)alloc((size_t)5 * 16384 * 2);
    (void)ws_size;  // ~59 MB total, well under the previously-proven budget

    int gN = (N + 255) / 256, gE = (E + 255) / 256;
    int gRows32 = (N + 31) / 32;
    int nScanBlocks = (N + 1023) / 1024;

    zero_ints<<<gN, 256, 0, stream>>>(cnt, N);
    count_deg<<<gE, 256, 0, stream>>>(dst, cnt, E);
    compute_dis<<<gN, 256, 0, stream>>>(cnt, dis, N);
    scan_block_sums<<<nScanBlocks, 256, 0, stream>>>(cnt, partials, N);
    scan_partials<<<1, 256, 0, stream>>>(partials, nScanBlocks, rp, N);
    scan_write<<<nScanBlocks, 256, 0, stream>>>(cnt, partials, rp, cursor, N);
    scatter_edges<<<gE, 256, 0, stream>>>(src, dst, dis, cursor, edata, E);
    build_h0<<<(N * 16 + 255) / 256, 256, 0, stream>>>(x, xm, h0, N);
    wsplit_kernel<<<5 * 16384 / 256, 256, 0, stream>>>(Wh, Wr1, whi, wlo);

    // layer 0 (in_dim=16): fused aggregate + K=16 GEMM -> relu -> fp16 bufA
    fused_layer0_kernel<<<gRows32, 256, 0, stream>>>(h0, rp, edata, dis, W0, b0, bufA, N);

    // hidden layers 1..3: fused aggregate + MFMA GEMM, ping-ponging bufA/bufB
    fused_layer_kernel<false><<<gRows32, 256, 0, stream>>>(
        bufA, rp, edata, dis, whi, wlo, bh, bufB,
        nullptr, nullptr, nullptr, nullptr, nullptr, nullptr, N);
    fused_layer_kernel<false><<<gRows32, 256, 0, stream>>>(
        bufB, rp, edata, dis, whi + 16384, wlo + 16384, bh + 128, bufA,
        nullptr, nullptr, nullptr, nullptr, nullptr, nullptr, N);
    fused_layer_kernel<false><<<gRows32, 256, 0, stream>>>(
        bufA, rp, edata, dis, whi + 2 * 16384, wlo + 2 * 16384, bh + 2 * 128, bufB,
        nullptr, nullptr, nullptr, nullptr, nullptr, nullptr, N);
    // final layer: fused aggregate + GEMM -> emb (fp32) + fused head -> pred
    fused_layer_kernel<true><<<gRows32, 256, 0, stream>>>(
        bufB, rp, edata, dis, whi + 3 * 16384, wlo + 3 * 16384, bh + 3 * 128, emb_out,
        whi + 4 * 16384, wlo + 4 * 16384, br1, Wr2, br2, pred_out, N);
}

// Round 11
// 464.912 us; speedup vs baseline: 1.0993x; 1.0993x over previous
//
#include <hip/hip_runtime.h>
#include <cstdint>
#include <cstddef>

typedef __attribute__((ext_vector_type(8))) short short8;
typedef __attribute__((ext_vector_type(4))) float f32x4;
typedef __attribute__((ext_vector_type(4))) _Float16 half4v;
typedef __attribute__((ext_vector_type(2))) _Float16 half2v;

// ---------------- bf16 split helpers (round-to-nearest-even) ----------------

__device__ inline unsigned short f2bf(float f) {
    unsigned int u = __float_as_uint(f);
    u = u + 0x7fff + ((u >> 16) & 1);
    return (unsigned short)(u >> 16);
}
__device__ inline float bf2f(unsigned short h) {
    return __uint_as_float(((unsigned int)h) << 16);
}
__device__ inline void split2(float v, unsigned short& hi, unsigned short& lo) {
    hi = f2bf(v);
    lo = f2bf(v - bf2f(hi));
}

// 32-bit-offset loads (avoid 64-bit per-lane address mul; saddr+voffset form)
__device__ __forceinline__ half2v ld_h2(const _Float16* p, unsigned off) {
    return *(const half2v*)((const char*)p + off);
}
__device__ __forceinline__ float ld_f(const float* p, unsigned off) {
    return *(const float*)((const char*)p + off);
}

// ---------------- preprocessing kernels ----------------

__global__ void zero_ints(int* p, int n) {
    int i = blockIdx.x * 256 + threadIdx.x;
    if (i < n) p[i] = 0;
}

__global__ void count_deg(const int* __restrict__ dst, int* __restrict__ cnt, int E) {
    int i = blockIdx.x * 256 + threadIdx.x;
    if (i < E) atomicAdd(&cnt[dst[i]], 1);
}

__global__ void compute_dis(const int* __restrict__ cnt, float* __restrict__ dis, int N) {
    int i = blockIdx.x * 256 + threadIdx.x;
    if (i < N) dis[i] = rsqrtf((float)cnt[i] + 1.0f);
}

// ---------------- 3-phase parallel exclusive scan over cnt -> rp, cursor ----------------

__global__ __launch_bounds__(256) void scan_block_sums(const int* __restrict__ cnt,
                                                       int* __restrict__ partials, int N) {
    __shared__ int s[256];
    int t = threadIdx.x;
    int base = blockIdx.x * 1024 + t * 4;
    int v = 0;
    if (base + 3 < N) {
        int4 d = *(const int4*)&cnt[base];
        v = d.x + d.y + d.z + d.w;
    } else {
        for (int j = 0; j < 4; ++j) if (base + j < N) v += cnt[base + j];
    }
    s[t] = v;
    __syncthreads();
    for (int off = 128; off > 0; off >>= 1) {
        if (t < off) s[t] += s[t + off];
        __syncthreads();
    }
    if (t == 0) partials[blockIdx.x] = s[0];
}

__global__ __launch_bounds__(256) void scan_partials(int* __restrict__ partials, int nb,
                                                     int* __restrict__ rp, int N) {
    __shared__ int s[256];
    int t = threadIdx.x;
    int base = t * 4;
    int v0 = 0, v1 = 0, v2 = 0, v3 = 0;
    if (base < nb)     v0 = partials[base];
    if (base + 1 < nb) v1 = partials[base + 1];
    if (base + 2 < nb) v2 = partials[base + 2];
    if (base + 3 < nb) v3 = partials[base + 3];
    s[t] = v0 + v1 + v2 + v3;
    __syncthreads();
    for (int off = 1; off < 256; off <<= 1) {
        int v = s[t];
        int u = (t >= off) ? s[t - off] : 0;
        __syncthreads();
        s[t] = v + u;
        __syncthreads();
    }
    int run = (t == 0) ? 0 : s[t - 1];
    if (base < nb)     { partials[base] = run;     run += v0; }
    if (base + 1 < nb) { partials[base + 1] = run; run += v1; }
    if (base + 2 < nb) { partials[base + 2] = run; run += v2; }
    if (base + 3 < nb) { partials[base + 3] = run; run += v3; }
    if (t == 255) rp[N] = s[255];
}

__global__ __launch_bounds__(256) void scan_write(const int* __restrict__ cnt,
                                                  const int* __restrict__ partials,
                                                  int* __restrict__ rp,
                                                  int* __restrict__ cursor, int N) {
    __shared__ int s[256];
    int t = threadIdx.x;
    int base = blockIdx.x * 1024 + t * 4;
    int v0 = 0, v1 = 0, v2 = 0, v3 = 0;
    if (base + 3 < N) {
        int4 d = *(const int4*)&cnt[base];
        v0 = d.x; v1 = d.y; v2 = d.z; v3 = d.w;
    } else {
        if (base < N)     v0 = cnt[base];
        if (base + 1 < N) v1 = cnt[base + 1];
        if (base + 2 < N) v2 = cnt[base + 2];
    }
    s[t] = v0 + v1 + v2 + v3;
    __syncthreads();
    for (int off = 1; off < 256; off <<= 1) {
        int v = s[t];
        int u = (t >= off) ? s[t - off] : 0;
        __syncthreads();
        s[t] = v + u;
        __syncthreads();
    }
    int run = partials[blockIdx.x] + ((t == 0) ? 0 : s[t - 1]);
    int4 o;
    o.x = run; run += v0;
    o.y = run; run += v1;
    o.z = run; run += v2;
    o.w = run; run += v3;
    if (base + 3 < N) {
        *(int4*)&rp[base] = o;
        *(int4*)&cursor[base] = o;
    } else {
        if (base < N)     { rp[base] = o.x;     cursor[base] = o.x; }
        if (base + 1 < N) { rp[base + 1] = o.y; cursor[base + 1] = o.y; }
        if (base + 2 < N) { rp[base + 2] = o.z; cursor[base + 2] = o.z; }
    }
}

// edata[pos] = (src, bitcast(norm)) — one 8B record per edge
__global__ void scatter_edges(const int* __restrict__ src, const int* __restrict__ dstv,
                              const float* __restrict__ dis, int* __restrict__ cursor,
                              int2* __restrict__ edata, int E) {
    int i = blockIdx.x * 256 + threadIdx.x;
    if (i < E) {
        int s = src[i], d = dstv[i];
        int pos = atomicAdd(&cursor[d], 1);
        edata[pos] = make_int2(s, __float_as_int(dis[s] * dis[d]));
    }
}

__global__ void build_h0(const float* __restrict__ x, const float* __restrict__ xm,
                         float* __restrict__ h0, int N) {
    int i = blockIdx.x * 256 + threadIdx.x;
    if (i < N * 16) {
        int node = i >> 4, f = i & 15;
        h0[i] = (f < 8) ? x[node * 10 + f] : xm[node * 10 + f - 8];
    }
}

// ---------------- W split into MFMA B-fragment order ----------------

__global__ __launch_bounds__(256) void wsplit_kernel(const float* __restrict__ Wh,
                                                     const float* __restrict__ Wr1,
                                                     unsigned short* __restrict__ whi,
                                                     unsigned short* __restrict__ wlo) {
    int g = blockIdx.x * 256 + threadIdx.x;   // 5*16384 entries
    int l = g >> 14;
    int idx = g & 16383;
    int j = idx & 7;
    int lane = (idx >> 3) & 63;
    int tcchunk = idx >> 9;                   // 0..31
    int tc = tcchunk & 7, chunk = tcchunk >> 3;
    int k = chunk * 32 + (lane >> 4) * 8 + j;
    int n = tc * 16 + (lane & 15);
    float v = (l < 4) ? Wh[l * 16384 + k * 128 + n] : Wr1[k * 128 + n];
    unsigned short hi, lo;
    split2(v, hi, lo);
    whi[g] = hi;
    wlo[g] = lo;
}

// ---------------- per-node aggregation bodies (forceinline; callers fully unroll
// so every array access is compile-time-constant — rule #20). Degree buckets are
// wave-uniform branches (deg uniform per wave): deg<=8 path skips the ~7 dummy
// clamped gathers + their address/cndmask VALU that the fixed 16-slot path pays
// for ~59% of nodes (Poisson mean 8). Removing +0.0 contributions is a numeric
// no-op (identical zeros were added in all prior passing rounds). ----------------

__device__ __forceinline__ float agg_node_l0(
    const float* __restrict__ h0, const int2* __restrict__ edata,
    const float* __restrict__ dis,
    int node, int beg, int deg, int es, int f, int N) {
    float acc = 0.f;
    if (node < N) {
        float di = dis[node];
        float sf = ld_f(h0, ((unsigned)node << 6) + (f << 2));
        acc = (es == 0) ? sf * (di * di) : 0.f;
        const int2* ep = edata + beg;
        if (deg > 0 && deg <= 8) {
            int2 rec[8];
            #pragma unroll
            for (int j = 0; j < 8; ++j) rec[j] = ep[j];
            int ixs = rec[0].x;
            float vv[2], nn[2];
            #pragma unroll
            for (int b = 0; b < 2; ++b) {
                int x0 = rec[b * 4 + 0].x, x1 = rec[b * 4 + 1].x;
                int x2 = rec[b * 4 + 2].x, x3 = rec[b * 4 + 3].x;
                int y0 = rec[b * 4 + 0].y, y1 = rec[b * 4 + 1].y;
                int y2 = rec[b * 4 + 2].y, y3 = rec[b * 4 + 3].y;
                int ix = (es == 0) ? x0 : (es == 1) ? x1 : (es == 2) ? x2 : x3;
                int iy = (es == 0) ? y0 : (es == 1) ? y1 : (es == 2) ? y2 : y3;
                int j = b * 4 + es;
                ix = (j < deg) ? ix : ixs;
                vv[b] = ld_f(h0, ((unsigned)ix << 6) + (f << 2));
                nn[b] = (j < deg) ? __int_as_float(iy) : 0.f;
            }
            acc += nn[0] * vv[0];
            acc += nn[1] * vv[1];
        } else if (deg > 8) {
            for (int eb = 0; eb < deg; eb += 16) {
                int2 rec[16];
                #pragma unroll
                for (int j = 0; j < 16; ++j) rec[j] = ep[eb + j];
                int c = min(deg - eb, 16);   // >= 1
                int ixs = rec[0].x;
                float vv[4], nn[4];
                #pragma unroll
                for (int b = 0; b < 4; ++b) {
                    int x0 = rec[b * 4 + 0].x, x1 = rec[b * 4 + 1].x;
                    int x2 = rec[b * 4 + 2].x, x3 = rec[b * 4 + 3].x;
                    int y0 = rec[b * 4 + 0].y, y1 = rec[b * 4 + 1].y;
                    int y2 = rec[b * 4 + 2].y, y3 = rec[b * 4 + 3].y;
                    int ix = (es == 0) ? x0 : (es == 1) ? x1 : (es == 2) ? x2 : x3;
                    int iy = (es == 0) ? y0 : (es == 1) ? y1 : (es == 2) ? y2 : y3;
                    int j = b * 4 + es;
                    ix = (j < c) ? ix : ixs;
                    vv[b] = ld_f(h0, ((unsigned)ix << 6) + (f << 2));
                    nn[b] = (j < c) ? __int_as_float(iy) : 0.f;
                }
                #pragma unroll
                for (int b = 0; b < 4; ++b) acc += nn[b] * vv[b];
            }
        }
    }
    acc += __shfl_xor(acc, 16);
    acc += __shfl_xor(acc, 32);
    return acc;
}

__device__ __forceinline__ void store_row_hidden(unsigned short* sAh, unsigned short* sAl,
                                                 int r, int ln, float a0, float a1) {
    unsigned short h0_, l0_, h1_, l1_;
    split2(a0, h0_, l0_);
    split2(a1, h1_, l1_);
    int bo = (r * 256 + ln * 4) ^ ((r & 7) << 4);
    ushort2 hh; hh.x = h0_; hh.y = h1_;
    ushort2 ll; ll.x = l0_; ll.y = l1_;
    *(ushort2*)((char*)sAh + bo) = hh;
    *(ushort2*)((char*)sAl + bo) = ll;
}

__device__ __forceinline__ void agg_node_hidden(
    const _Float16* __restrict__ hin, const int2* __restrict__ edata,
    const float* __restrict__ dis,
    int node, int beg, int deg, int ln, int N,
    unsigned short* sAh, unsigned short* sAl, int r) {
    float a0 = 0.f, a1 = 0.f;
    if (node < N) {
        float di = dis[node];
        float sc = di * di;
        unsigned lb = (unsigned)(ln << 2);
        half2v sv = ld_h2(hin, ((unsigned)node << 8) + lb);
        a0 = (float)sv[0] * sc;
        a1 = (float)sv[1] * sc;
        const int2* ep = edata + beg;
        if (deg > 0 && deg <= 8) {
            int2 rec[8];
            #pragma unroll
            for (int j = 0; j < 8; ++j) rec[j] = ep[j];
            int ix0 = rec[0].x;
            half2v va[8];
            #pragma unroll
            for (int j = 0; j < 8; ++j) {
                int ix = (j < deg) ? rec[j].x : ix0;
                va[j] = ld_h2(hin, ((unsigned)ix << 8) + lb);
            }
            #pragma unroll
            for (int j = 0; j < 8; ++j) {
                float nr = (j < deg) ? __int_as_float(rec[j].y) : 0.f;
                a0 += nr * (float)va[j][0];
                a1 += nr * (float)va[j][1];
            }
        } else if (deg > 8) {
            int2 rec[16];
            #pragma unroll
            for (int j = 0; j < 16; ++j) rec[j] = ep[j];
            int c = min(deg, 16);
            int ix0 = rec[0].x;
            half2v va[16];
            #pragma unroll
            for (int j = 0; j < 16; ++j) {
                int ix = (j < c) ? rec[j].x : ix0;
                va[j] = ld_h2(hin, ((unsigned)ix << 8) + lb);
            }
            #pragma unroll
            for (int j = 0; j < 16; ++j) {
                float nr = (j < c) ? __int_as_float(rec[j].y) : 0.f;
                a0 += nr * (float)va[j][0];
                a1 += nr * (float)va[j][1];
            }
            for (int e = 16; e < deg; ++e) {
                int2 rr2 = ep[e];
                half2v v = ld_h2(hin, ((unsigned)rr2.x << 8) + lb);
                float nr = __int_as_float(rr2.y);
                a0 += nr * (float)v[0];
                a1 += nr * (float)v[1];
            }
        }
    }
    store_row_hidden(sAh, sAl, r, ln, a0, a1);
}

// ---------------- fused layer 0: agg16 (wave-scalar) + K=16 VALU GEMM + relu ----------------
// 32 nodes/block, 4 waves. Phase 1: one wave per node, 64 lanes = 4 edge-slots(es)
// x 16 features(f). rp[9] hoisted in ONE round trip; 8-node loop FULLY UNROLLED so
// rr[] is constant-indexed (SGPRs, no scratch — R6/R7 lesson).
// Phase 2: 32x128 output, 256 threads x 16 cols each, W0 staged in LDS.

__global__ __launch_bounds__(256, 8) void fused_layer0_kernel(
    const float* __restrict__ h0,
    const int* __restrict__ rp, const int2* __restrict__ edata,
    const float* __restrict__ dis,
    const float* __restrict__ W0, const float* __restrict__ b0,
    _Float16* __restrict__ hout, int N) {
    __shared__ float sA[32][17];
    __shared__ float sW[2048];
    int t = threadIdx.x;
    int node0 = blockIdx.x * 32;
    // stage W0 (16 x 128)
    for (int i = t * 4; i < 2048; i += 1024)
        *(float4*)&sW[i] = *(const float4*)&W0[i];

    // ---- phase 1 ----
    {
        int wv = __builtin_amdgcn_readfirstlane(t >> 6);
        int ln = t & 63;
        int es = ln >> 4, f = ln & 15;
        int base = node0 + wv * 8;
        int rr[9];
        #pragma unroll
        for (int i = 0; i < 9; ++i) rr[i] = rp[min(base + i, N)];
        #pragma unroll
        for (int it = 0; it < 8; ++it) {
            float acc = agg_node_l0(h0, edata, dis, base + it, rr[it],
                                    rr[it + 1] - rr[it], es, f, N);
            if (es == 0) sA[wv * 8 + it][f] = acc;
        }
    }
    __syncthreads();

    // ---- phase 2: K=16 GEMM ----
    int r2 = t >> 3;
    int c0 = (t & 7) * 16;
    float a16[16];
    #pragma unroll
    for (int c = 0; c < 16; ++c) a16[c] = 0.f;
    #pragma unroll
    for (int k = 0; k < 16; ++k) {
        float a = sA[r2][k];
        #pragma unroll
        for (int c = 0; c < 16; ++c) a16[c] += a * sW[k * 128 + c0 + c];
    }
    int row = node0 + r2;
    if (row < N) {
        #pragma unroll
        for (int cc = 0; cc < 16; cc += 4) {
            half4v o;
            #pragma unroll
            for (int u = 0; u < 4; ++u)
                o[u] = (_Float16)fmaxf(a16[cc + u] + b0[c0 + cc + u], 0.f);
            *(half4v*)&hout[(size_t)row * 128 + c0 + cc] = o;
        }
    }
}

// ---------------- fused layer: aggregate(hin) -> LDS split-bf16 -> MFMA GEMM ----------------
// 32 nodes/block, 16 KB LDS, 8 blocks/CU.
// Phase 1 (wave-scalar, R9-proven structure + degree buckets + 32-bit offsets):
// one wave per node (lane ln owns features 2ln,2ln+1). rp[9] hoisted (one round
// trip, fully unrolled -> constant indices, rule #20). Per node: 8- or 16-record
// wave-uniform scalar burst + gathers in flight; j>=deg gathers clamped (norm 0
// -> exact no-op). deg>16 tail serial. FP order per node: self, edges ascending
// — bit-identical to R5/R8/R9. Burst may read <=120B past edata end: mapped
// partials region, never used as an address.
// Phase 2: 4 waves = (row-group rg, col-half ch); each wave does 16 rows x 4 tc.
// LAST: emb fp32 + fused head (Wr1 MFMA + Wr2 reduce; cross-ch partials via LDS).

template <bool LAST>
__global__ __launch_bounds__(256, 8) void fused_layer_kernel(
    const _Float16* __restrict__ hin,
    const int* __restrict__ rp, const int2* __restrict__ edata,
    const float* __restrict__ dis,
    const unsigned short* __restrict__ whi, const unsigned short* __restrict__ wlo,
    const float* __restrict__ bias,
    void* __restrict__ outv,
    const unsigned short* __restrict__ w1hi, const unsigned short* __restrict__ w1lo,
    const float* __restrict__ br1, const float* __restrict__ Wr2,
    const float* __restrict__ br2, float* __restrict__ pred,
    int N) {
    __shared__ unsigned short sAh[4096];   // 32 rows x 128 cols, swizzled
    __shared__ unsigned short sAl[4096];
    int t = threadIdx.x;
    int node0 = blockIdx.x * 32;

    // ---- phase 1: aggregation into LDS (one wave per node) ----
    {
        int wv1 = __builtin_amdgcn_readfirstlane(t >> 6);
        int ln = t & 63;
        int base = node0 + wv1 * 8;
        int rr[9];
        #pragma unroll
        for (int i = 0; i < 9; ++i) rr[i] = rp[min(base + i, N)];
        #pragma unroll
        for (int it = 0; it < 8; ++it)
            agg_node_hidden(hin, edata, dis, base + it, rr[it],
                            rr[it + 1] - rr[it], ln, N, sAh, sAl, wv1 * 8 + it);
    }
    __syncthreads();

    // ---- phase 2: MFMA GEMM from LDS ----
    int wv = t >> 6, ln2 = t & 63;
    int m = ln2 & 15, q = ln2 >> 4;
    int rg = wv & 1, ch = wv >> 1;
    int rloc = rg * 16 + m;
    int tcb = ch * 4;

    f32x4 acc[4];
    #pragma unroll
    for (int i = 0; i < 4; ++i) acc[i] = (f32x4)(0.f);

    #pragma unroll
    for (int chunk = 0; chunk < 4; ++chunk) {
        int bo = (rloc * 256 + q * 16 + chunk * 64) ^ ((rloc & 7) << 4);
        short8 af = *(const short8*)((const char*)sAh + bo);
        short8 lf = *(const short8*)((const char*)sAl + bo);
        const unsigned short* wb = whi + (size_t)(chunk * 8 + tcb) * 512 + ln2 * 8;
        const unsigned short* wc = wlo + (size_t)(chunk * 8 + tcb) * 512 + ln2 * 8;
        #pragma unroll
        for (int j = 0; j < 4; ++j) {
            short8 wh = *(const short8*)(wb + j * 512);
            short8 wl = *(const short8*)(wc + j * 512);
            acc[j] = __builtin_amdgcn_mfma_f32_16x16x32_bf16(af, wh, acc[j], 0, 0, 0);
            acc[j] = __builtin_amdgcn_mfma_f32_16x16x32_bf16(lf, wh, acc[j], 0, 0, 0);
            acc[j] = __builtin_amdgcn_mfma_f32_16x16x32_bf16(af, wl, acc[j], 0, 0, 0);
        }
    }

    // C/D layout: col = lane&15, row = (lane>>4)*4 + reg  [m89/m91-verified]
    int crow = node0 + rg * 16 + q * 4;

    if constexpr (!LAST) {
        _Float16* hout = (_Float16*)outv;
        #pragma unroll
        for (int j = 0; j < 4; ++j) {
            int col = (tcb + j) * 16 + m;
            float b = bias[col];
            #pragma unroll
            for (int r = 0; r < 4; ++r) {
                int rr = crow + r;
                if (rr < N) {
                    float v = fmaxf(acc[j][r] + b, 0.f);
                    hout[(size_t)rr * 128 + col] = (_Float16)v;
                }
            }
        }
    } else {
        __shared__ float pbuf[2][16][3];
        // emb write: fp32 nontemporal, no relu
        float* emb = (float*)outv;
        #pragma unroll
        for (int j = 0; j < 4; ++j) {
            int col = (tcb + j) * 16 + m;
            float b = bias[col];
            #pragma unroll
            for (int r = 0; r < 4; ++r) {
                int rr = crow + r;
                if (rr < N)
                    __builtin_nontemporal_store(acc[j][r] + b, &emb[(size_t)rr * 128 + col]);
            }
        }
        __syncthreads();  // all phase-2 LDS reads complete before overwrite
        // relu + split acc back into LDS (C-layout -> A-layout redistribution)
        #pragma unroll
        for (int j = 0; j < 4; ++j) {
            int col = (tcb + j) * 16 + m;
            float b = bias[col];
            #pragma unroll
            for (int r = 0; r < 4; ++r) {
                int r2 = rg * 16 + q * 4 + r;
                float v = fmaxf(acc[j][r] + b, 0.f);
                unsigned short hi, lo;
                split2(v, hi, lo);
                int bo = (r2 * 256 + col * 2) ^ ((r2 & 7) << 4);
                *(unsigned short*)((char*)sAh + bo) = hi;
                *(unsigned short*)((char*)sAl + bo) = lo;
            }
        }
        __syncthreads();
        // head MFMA: relu(emb) @ Wr1 (this wave's 4 tc columns)
        f32x4 acc2[4];
        #pragma unroll
        for (int i = 0; i < 4; ++i) acc2[i] = (f32x4)(0.f);
        #pragma unroll
        for (int chunk = 0; chunk < 4; ++chunk) {
            int bo = (rloc * 256 + q * 16 + chunk * 64) ^ ((rloc & 7) << 4);
            short8 af = *(const short8*)((const char*)sAh + bo);
            short8 lf = *(const short8*)((const char*)sAl + bo);
            const unsigned short* wb = w1hi + (size_t)(chunk * 8 + tcb) * 512 + ln2 * 8;
            const unsigned short* wc = w1lo + (size_t)(chunk * 8 + tcb) * 512 + ln2 * 8;
            #pragma unroll
            for (int j = 0; j < 4; ++j) {
                short8 wh = *(const short8*)(wb + j * 512);
                short8 wl = *(const short8*)(wc + j * 512);
                acc2[j] = __builtin_amdgcn_mfma_f32_16x16x32_bf16(af, wh, acc2[j], 0, 0, 0);
                acc2[j] = __builtin_amdgcn_mfma_f32_16x16x32_bf16(lf, wh, acc2[j], 0, 0, 0);
                acc2[j] = __builtin_amdgcn_mfma_f32_16x16x32_bf16(af, wl, acc2[j], 0, 0, 0);
            }
        }
        // relu(h @ Wr1 + br1) @ Wr2 + br2: partial over this wave's 64 cols
        float p0[4] = {0.f, 0.f, 0.f, 0.f};
        float p1[4] = {0.f, 0.f, 0.f, 0.f};
        float p2[4] = {0.f, 0.f, 0.f, 0.f};
        #pragma unroll
        for (int j = 0; j < 4; ++j) {
            int col = (tcb + j) * 16 + m;
            float b1 = br1[col];
            float w0 = Wr2[col * 3 + 0], w1 = Wr2[col * 3 + 1], w2 = Wr2[col * 3 + 2];
            #pragma unroll
            for (int r = 0; r < 4; ++r) {
                float hv = fmaxf(acc2[j][r] + b1, 0.f);
                p0[r] += hv * w0;
                p1[r] += hv * w1;
                p2[r] += hv * w2;
            }
        }
        #pragma unroll
        for (int mask = 1; mask < 16; mask <<= 1) {
            #pragma unroll
            for (int r = 0; r < 4; ++r) {
                p0[r] += __shfl_xor(p0[r], mask);
                p1[r] += __shfl_xor(p1[r], mask);
                p2[r] += __shfl_xor(p2[r], mask);
            }
        }
        if (ch == 1 && m == 0) {
            #pragma unroll
            for (int r = 0; r < 4; ++r) {
                pbuf[rg][q * 4 + r][0] = p0[r];
                pbuf[rg][q * 4 + r][1] = p1[r];
                pbuf[rg][q * 4 + r][2] = p2[r];
            }
        }
        __syncthreads();
        if (ch == 0 && m == 0) {
            #pragma unroll
            for (int r = 0; r < 4; ++r) {
                int rr = crow + r;
                if (rr < N) {
                    float o0 = p0[r] + pbuf[rg][q * 4 + r][0] + br2[0];
                    float o1 = p1[r] + pbuf[rg][q * 4 + r][1] + br2[1];
                    float o2 = p2[r] + pbuf[rg][q * 4 + r][2] + br2[2];
                    __builtin_nontemporal_store(o0, &pred[(size_t)rr * 3 + 0]);
                    __builtin_nontemporal_store(o1, &pred[(size_t)rr * 3 + 1]);
                    __builtin_nontemporal_store(o2, &pred[(size_t)rr * 3 + 2]);
                }
            }
        }
    }
}

// ---------------- launch ----------------

extern "C" void kernel_launch(void* const* d_in, const int* in_sizes, int n_in,
                              void* d_out, int out_size, void* d_ws, size_t ws_size,
                              hipStream_t stream) {
    const float* x   = (const float*)d_in[0];
    const float* xm  = (const float*)d_in[1];
    const int*   ei  = (const int*)d_in[2];
    const float* W0  = (const float*)d_in[3];
    const float* b0  = (const float*)d_in[4];
    const float* Wh  = (const float*)d_in[5];
    const float* bh  = (const float*)d_in[6];
    const float* Wr1 = (const float*)d_in[7];
    const float* br1 = (const float*)d_in[8];
    const float* Wr2 = (const float*)d_in[9];
    const float* br2 = (const float*)d_in[10];
    float* out = (float*)d_out;

    int N = in_sizes[0] / 10;
    int E = in_sizes[2] / 2;
    const int* src = ei;
    const int* dst = ei + E;

    float* emb_out  = out;                   // N x 128 (final GCN layer writes here)
    float* pred_out = out + (size_t)N * 128; // N x 3

    char* ws = (char*)d_ws;
    size_t off = 0;
    auto alloc = [&](size_t bytes) -> void* {
        void* p = ws + off;
        off += (bytes + 255) & ~(size_t)255;
        return p;
    };
    // h ping-pong buffers (fp16, 25.6 MB each). h0 aliases bufB's head
    // (dead before bufB's first write at layer l=0's output).
    _Float16* bufA = (_Float16*)alloc((size_t)N * 128 * 2);
    _Float16* bufB = (_Float16*)alloc((size_t)N * 128 * 2);
    float* h0       = (float*)bufB;
    int*   cnt      = (int*)alloc((size_t)N * 4);
    float* dis      = (float*)alloc((size_t)N * 4);
    int*   rp       = (int*)alloc((size_t)(N + 1) * 4);
    int*   cursor   = (int*)alloc((size_t)N * 4);
    int2*  edata    = (int2*)alloc((size_t)E * 8);
    int*   partials = (int*)alloc((size_t)1024 * 4);
    unsigned short* whi = (unsigned short*)alloc((size_t)5 * 16384 * 2);
    unsigned short* wlo = (unsigned short*)alloc((size_t)5 * 16384 * 2);
    (void)ws_size;  // ~59 MB total, well under the previously-proven budget

    int gN = (N + 255) / 256, gE = (E + 255) / 256;
    int gRows32 = (N + 31) / 32;
    int nScanBlocks = (N + 1023) / 1024;

    zero_ints<<<gN, 256, 0, stream>>>(cnt, N);
    count_deg<<<gE, 256, 0, stream>>>(dst, cnt, E);
    compute_dis<<<gN, 256, 0, stream>>>(cnt, dis, N);
    scan_block_sums<<<nScanBlocks, 256, 0, stream>>>(cnt, partials, N);
    scan_partials<<<1, 256, 0, stream>>>(partials, nScanBlocks, rp, N);
    scan_write<<<nScanBlocks, 256, 0, stream>>>(cnt, partials, rp, cursor, N);
    scatter_edges<<<gE, 256, 0, stream>>>(src, dst, dis, cursor, edata, E);
    build_h0<<<(N * 16 + 255) / 256, 256, 0, stream>>>(x, xm, h0, N);
    wsplit_kernel<<<5 * 16384 / 256, 256, 0, stream>>>(Wh, Wr1, whi, wlo);

    // layer 0 (in_dim=16): fused aggregate + K=16 GEMM -> relu -> fp16 bufA
    fused_layer0_kernel<<<gRows32, 256, 0, stream>>>(h0, rp, edata, dis, W0, b0, bufA, N);

    // hidden layers 1..3: fused aggregate + MFMA GEMM, ping-ponging bufA/bufB
    fused_layer_kernel<false><<<gRows32, 256, 0, stream>>>(
        bufA, rp, edata, dis, whi, wlo, bh, bufB,
        nullptr, nullptr, nullptr, nullptr, nullptr, nullptr, N);
    fused_layer_kernel<false><<<gRows32, 256, 0, stream>>>(
        bufB, rp, edata, dis, whi + 16384, wlo + 16384, bh + 128, bufA,
        nullptr, nullptr, nullptr, nullptr, nullptr, nullptr, N);
    fused_layer_kernel<false><<<gRows32, 256, 0, stream>>>(
        bufA, rp, edata, dis, whi + 2 * 16384, wlo + 2 * 16384, bh + 2 * 128, bufB,
        nullptr, nullptr, nullptr, nullptr, nullptr, nullptr, N);
    // final layer: fused aggregate + GEMM -> emb (fp32) + fused head -> pred
    fused_layer_kernel<true><<<gRows32, 256, 0, stream>>>(
        bufB, rp, edata, dis, whi + 3 * 16384, wlo + 3 * 16384, bh + 3 * 128, emb_out,
        whi + 4 * 16384, wlo + 4 * 16384, br1, Wr2, br2, pred_out, N);
}